// Round 1
// baseline (3165.414 us; speedup 1.0000x reference)
//
#include <hip/hip_runtime.h>
#include <hip/hip_bf16.h>

#define TILE_E 32
#define WSTRIDE 132   // 128 + 4 pad: lane stride 132 floats -> bank step 4 -> minimal b128 pattern

// ---------------------------------------------------------------------------
// Shared helpers
// ---------------------------------------------------------------------------

// GEMM tile: Y[32][128] = sX[32][*] @ W (sWT is W transposed: sWT[c][k]).
// Thread (lc = tid&63, rg = tid>>6) computes rows rg*8..rg*8+7, cols lc and lc+64.
__device__ __forceinline__ void gemm_tile(const float* __restrict__ sX,
                                          const float* __restrict__ sWT,
                                          int lc, int rg,
                                          float acc0[8], float acc1[8])
{
    const float* w0p = sWT + lc * WSTRIDE;
    const float* w1p = sWT + (lc + 64) * WSTRIDE;
    const float* xp  = sX + rg * 8 * WSTRIDE;
#pragma unroll 4
    for (int k = 0; k < 128; k += 4) {
        float4 w0 = *(const float4*)(w0p + k);
        float4 w1 = *(const float4*)(w1p + k);
#pragma unroll
        for (int j = 0; j < 8; ++j) {
            float4 x = *(const float4*)(xp + j * WSTRIDE + k);
            acc0[j] = fmaf(x.x, w0.x, acc0[j]);
            acc0[j] = fmaf(x.y, w0.y, acc0[j]);
            acc0[j] = fmaf(x.z, w0.z, acc0[j]);
            acc0[j] = fmaf(x.w, w0.w, acc0[j]);
            acc1[j] = fmaf(x.x, w1.x, acc1[j]);
            acc1[j] = fmaf(x.y, w1.y, acc1[j]);
            acc1[j] = fmaf(x.z, w1.z, acc1[j]);
            acc1[j] = fmaf(x.w, w1.w, acc1[j]);
        }
    }
}

// Stage 128x128 weight matrix (row-major [k][c]) transposed into sWT[c][k].
// Each thread owns column c = tid&127, k0 = tid>>7, writes k = k0 + 2j.
// Global reads coalesced; LDS writes stride-132 -> conflict-minimal.
__device__ __forceinline__ void stage_wt(const float* __restrict__ W,
                                         float* __restrict__ sWT, int tid)
{
    const int c  = tid & 127;
    const int k0 = tid >> 7;
    float*       dst = sWT + c * WSTRIDE + k0;
    const float* src = W + tid;
    float v[16];
#pragma unroll
    for (int p = 0; p < 4; ++p) {
#pragma unroll
        for (int i = 0; i < 16; ++i) v[i] = src[(p * 16 + i) * 256];
#pragma unroll
        for (int i = 0; i < 16; ++i) dst[(p * 16 + i) * 2] = v[i];
    }
}

// Per-row GroupNorm(ng=1) on accumulators + optional relu, write to LDS dst.
__device__ __forceinline__ void gn_rows_lds(const float acc0[8], const float acc1[8],
                                            float gw0, float gw1, float gb0, float gb1,
                                            bool relu, float* __restrict__ dst,
                                            int lc, int rg)
{
#pragma unroll
    for (int j = 0; j < 8; ++j) {
        float s1 = acc0[j] + acc1[j];
        float s2 = acc0[j] * acc0[j] + acc1[j] * acc1[j];
#pragma unroll
        for (int off = 32; off >= 1; off >>= 1) {
            s1 += __shfl_xor(s1, off);
            s2 += __shfl_xor(s2, off);
        }
        float m   = s1 * (1.f / 128.f);
        float var = fmaxf(s2 * (1.f / 128.f) - m * m, 0.f);
        float isc = rsqrtf(var + 1e-5f);
        float y0  = (acc0[j] - m) * isc * gw0 + gb0;
        float y1  = (acc1[j] - m) * isc * gw1 + gb1;
        if (relu) { y0 = fmaxf(y0, 0.f); y1 = fmaxf(y1, 0.f); }
        int r = rg * 8 + j;
        dst[r * WSTRIDE + lc]      = y0;
        dst[r * WSTRIDE + lc + 64] = y1;
    }
}

// ---------------------------------------------------------------------------
// K0/K1: per-row GEMM  Y = f(X @ W), f = identity or relu(gn(.))
// ---------------------------------------------------------------------------
__global__ __launch_bounds__(256) void rowgemm_kernel(
    const float* __restrict__ X, const float* __restrict__ W,
    const float* __restrict__ gw, const float* __restrict__ gb,
    float* __restrict__ Y, int n, int gn_relu)
{
    __shared__ float sWT[128 * WSTRIDE];
    __shared__ float sX[TILE_E * WSTRIDE];
    const int tid  = threadIdx.x;
    const int base = blockIdx.x * TILE_E;

    {   // stage X rows
        int r = tid >> 3, c0 = (tid & 7) * 16;
        int row = base + r;
        if (row < n) {
            const float* src = X + (size_t)row * 128 + c0;
            float*       dst = sX + r * WSTRIDE + c0;
#pragma unroll
            for (int i = 0; i < 4; ++i)
                *(float4*)(dst + i * 4) = *(const float4*)(src + i * 4);
        }
    }
    stage_wt(W, sWT, tid);
    __syncthreads();

    const int lc = tid & 63, rg = tid >> 6;
    float acc0[8] = {0,0,0,0,0,0,0,0}, acc1[8] = {0,0,0,0,0,0,0,0};
    gemm_tile(sX, sWT, lc, rg, acc0, acc1);

    if (gn_relu) {
        float gw0 = gw[lc], gw1 = gw[lc + 64], gb0 = gb[lc], gb1 = gb[lc + 64];
#pragma unroll
        for (int j = 0; j < 8; ++j) {
            float s1 = acc0[j] + acc1[j];
            float s2 = acc0[j] * acc0[j] + acc1[j] * acc1[j];
#pragma unroll
            for (int off = 32; off >= 1; off >>= 1) {
                s1 += __shfl_xor(s1, off);
                s2 += __shfl_xor(s2, off);
            }
            float m   = s1 * (1.f / 128.f);
            float var = fmaxf(s2 * (1.f / 128.f) - m * m, 0.f);
            float isc = rsqrtf(var + 1e-5f);
            int row = base + rg * 8 + j;
            if (row < n) {
                float y0 = fmaxf((acc0[j] - m) * isc * gw0 + gb0, 0.f);
                float y1 = fmaxf((acc1[j] - m) * isc * gw1 + gb1, 0.f);
                Y[(size_t)row * 128 + lc]      = y0;
                Y[(size_t)row * 128 + lc + 64] = y1;
            }
        }
    } else {
#pragma unroll
        for (int j = 0; j < 8; ++j) {
            int row = base + rg * 8 + j;
            if (row < n) {
                Y[(size_t)row * 128 + lc]      = acc0[j];
                Y[(size_t)row * 128 + lc + 64] = acc1[j];
            }
        }
    }
}

// ---------------------------------------------------------------------------
// K2: fused per-edge kernel
// ---------------------------------------------------------------------------
__global__ __launch_bounds__(256) void edge_kernel(
    const float* __restrict__ agt_ctrs, const float* __restrict__ ctx_ctrs,
    const int* __restrict__ hi, const int* __restrict__ wi,
    const float* __restrict__ qsrc,   // Q_all (precomputed) or agts (fallback)
    const float* __restrict__ ctx,
    const float* __restrict__ dist_w1, const float* __restrict__ dist_b1,
    const float* __restrict__ dist_w2,
    const float* __restrict__ dist_gw, const float* __restrict__ dist_gb,
    const float* __restrict__ q_w,
    const float* __restrict__ q_gw, const float* __restrict__ q_gb,
    const float* __restrict__ ctx_w1,
    const float* __restrict__ ctx_gw, const float* __restrict__ ctx_gb,
    const float* __restrict__ ctx_w2,
    float* __restrict__ out, int E, int numTiles, int q_pre)
{
    __shared__ float sWT[128 * WSTRIDE];       // 67.6 KB, cycled through 5 weight mats
    __shared__ float sH[TILE_E * WSTRIDE];     // h1, later reused for m
    __shared__ float sD[TILE_E * WSTRIDE];
    __shared__ float sQ[TILE_E * WSTRIDE];
    __shared__ float sC[TILE_E * WSTRIDE];
    __shared__ int   sHi[TILE_E];
    __shared__ int   sWiA[TILE_E];
    __shared__ float sDx[TILE_E], sDy[TILE_E];

    const int tid = threadIdx.x;
    const int lc = tid & 63, rg = tid >> 6;

    // hoisted per-column GN params (fixed per thread across tiles)
    const float dgw0 = dist_gw[lc], dgw1 = dist_gw[lc + 64];
    const float dgb0 = dist_gb[lc], dgb1 = dist_gb[lc + 64];
    const float cgw0 = ctx_gw[lc],  cgw1 = ctx_gw[lc + 64];
    const float cgb0 = ctx_gb[lc],  cgb1 = ctx_gb[lc + 64];
    float qgw0 = 0, qgw1 = 0, qgb0 = 0, qgb1 = 0;
    if (!q_pre) { qgw0 = q_gw[lc]; qgw1 = q_gw[lc + 64]; qgb0 = q_gb[lc]; qgb1 = q_gb[lc + 64]; }
    // hoisted dist_w1/b1 column (phase-1 mapping: c = tid&127)
    const int   hc  = tid & 127;
    const int   hrg = tid >> 7;
    const float w1x = dist_w1[hc], w1y = dist_w1[128 + hc], b1c = dist_b1[hc];

    for (int tile = blockIdx.x; tile < numTiles; tile += gridDim.x) {
        const int base = tile * TILE_E;
        __syncthreads();   // protect LDS vs previous iteration consumers
        if (tid < TILE_E) {
            int e = base + tid;
            int h = 0, w = 0;
            if (e < E) { h = hi[e]; w = wi[e]; }
            sHi[tid]  = h;
            sWiA[tid] = w;
            sDx[tid] = agt_ctrs[2 * h]     - ctx_ctrs[2 * w];
            sDy[tid] = agt_ctrs[2 * h + 1] - ctx_ctrs[2 * w + 1];
        }
        __syncthreads();

        {   // gather Q and C rows (8 threads per row, 16 floats each)
            int r = tid >> 3, c0 = (tid & 7) * 16;
            int h = sHi[r], w = sWiA[r];
            const float* qs = qsrc + (size_t)h * 128 + c0;
            const float* cs = ctx  + (size_t)w * 128 + c0;
            float* qd = sQ + r * WSTRIDE + c0;
            float* cd = sC + r * WSTRIDE + c0;
#pragma unroll
            for (int i = 0; i < 4; ++i) {
                *(float4*)(qd + i * 4) = *(const float4*)(qs + i * 4);
                *(float4*)(cd + i * 4) = *(const float4*)(cs + i * 4);
            }
        }
        {   // phase 1: h1 = relu(d2 @ dist_w1 + b1), mapping c = tid&127
#pragma unroll
            for (int j = 0; j < 16; ++j) {
                int r = hrg * 16 + j;
                float v = fmaf(sDx[r], w1x, fmaf(sDy[r], w1y, b1c));
                sH[r * WSTRIDE + hc] = fmaxf(v, 0.f);
            }
        }

        if (!q_pre) {   // fallback: compute q = relu(gn(agts[hi] @ q_w)) in-kernel
            __syncthreads();
            stage_wt(q_w, sWT, tid);
            __syncthreads();
            float a0[8] = {0,0,0,0,0,0,0,0}, a1[8] = {0,0,0,0,0,0,0,0};
            gemm_tile(sQ, sWT, lc, rg, a0, a1);
            __syncthreads();   // all reads of sQ done before overwrite
            gn_rows_lds(a0, a1, qgw0, qgw1, qgb0, qgb1, true, sQ, lc, rg);
        }

        // d = relu(gn(h1 @ dist_w2))
        __syncthreads();
        stage_wt(dist_w2, sWT, tid);
        __syncthreads();
        {
            float a0[8] = {0,0,0,0,0,0,0,0}, a1[8] = {0,0,0,0,0,0,0,0};
            gemm_tile(sH, sWT, lc, rg, a0, a1);
            gn_rows_lds(a0, a1, dgw0, dgw1, dgb0, dgb1, true, sD, lc, rg);
        }

        // m = relu(gn(d @ W1d + q @ W1q + c @ W1c))   (ctx_w1 in 3 chunks)
        float m0[8] = {0,0,0,0,0,0,0,0}, m1[8] = {0,0,0,0,0,0,0,0};
        __syncthreads();
        stage_wt(ctx_w1, sWT, tid);
        __syncthreads();
        gemm_tile(sD, sWT, lc, rg, m0, m1);
        __syncthreads();
        stage_wt(ctx_w1 + 128 * 128, sWT, tid);
        __syncthreads();
        gemm_tile(sQ, sWT, lc, rg, m0, m1);
        __syncthreads();
        stage_wt(ctx_w1 + 2 * 128 * 128, sWT, tid);
        __syncthreads();
        gemm_tile(sC, sWT, lc, rg, m0, m1);
        gn_rows_lds(m0, m1, cgw0, cgw1, cgb0, cgb1, true, sH, lc, rg);  // sH now holds m

        // m2 = m @ ctx_w2 ; scatter-add into out[hi]
        __syncthreads();
        stage_wt(ctx_w2, sWT, tid);
        __syncthreads();
        {
            float a0[8] = {0,0,0,0,0,0,0,0}, a1[8] = {0,0,0,0,0,0,0,0};
            gemm_tile(sH, sWT, lc, rg, a0, a1);
#pragma unroll
            for (int j = 0; j < 8; ++j) {
                int r = rg * 8 + j;
                int e = base + r;
                if (e < E) {
                    int h = sHi[r];
                    atomicAdd(&out[(size_t)h * 128 + lc],      a0[j]);
                    atomicAdd(&out[(size_t)h * 128 + lc + 64], a1[j]);
                }
            }
        }
    }
}

// ---------------------------------------------------------------------------
// K3: final row-wise:  out = relu(gn(relu(gn(acc)) @ lin_w) + res)   (in-place)
// ---------------------------------------------------------------------------
__global__ __launch_bounds__(256) void final_kernel(
    const float* __restrict__ agts,
    const float* __restrict__ norm_w, const float* __restrict__ norm_b,
    const float* __restrict__ lin_w,
    const float* __restrict__ lin_gw, const float* __restrict__ lin_gb,
    float* __restrict__ out, int n)
{
    __shared__ float sWT[128 * WSTRIDE];
    __shared__ float sX[TILE_E * WSTRIDE];
    const int tid  = threadIdx.x;
    const int base = blockIdx.x * TILE_E;

    {   // load acc rows, per-row GN(norm)+relu -> sX
        int r = tid >> 3, c0 = (tid & 7) * 16;
        int row = base + r;
        if (row < n) {
            const float* src = out + (size_t)row * 128 + c0;
            float vals[16];
            float s1 = 0.f, s2 = 0.f;
#pragma unroll
            for (int i = 0; i < 16; ++i) {
                float v = src[i];
                vals[i] = v; s1 += v; s2 += v * v;
            }
#pragma unroll
            for (int off = 4; off >= 1; off >>= 1) {
                s1 += __shfl_xor(s1, off);
                s2 += __shfl_xor(s2, off);
            }
            float m   = s1 * (1.f / 128.f);
            float var = fmaxf(s2 * (1.f / 128.f) - m * m, 0.f);
            float isc = rsqrtf(var + 1e-5f);
            float* dst = sX + r * WSTRIDE + c0;
#pragma unroll
            for (int i = 0; i < 16; ++i) {
                int c = c0 + i;
                float y = (vals[i] - m) * isc * norm_w[c] + norm_b[c];
                dst[i] = fmaxf(y, 0.f);
            }
        }
    }
    stage_wt(lin_w, sWT, tid);
    __syncthreads();

    const int lc = tid & 63, rg = tid >> 6;
    float acc0[8] = {0,0,0,0,0,0,0,0}, acc1[8] = {0,0,0,0,0,0,0,0};
    gemm_tile(sX, sWT, lc, rg, acc0, acc1);

    const float lgw0 = lin_gw[lc], lgw1 = lin_gw[lc + 64];
    const float lgb0 = lin_gb[lc], lgb1 = lin_gb[lc + 64];
#pragma unroll
    for (int j = 0; j < 8; ++j) {
        float s1 = acc0[j] + acc1[j];
        float s2 = acc0[j] * acc0[j] + acc1[j] * acc1[j];
#pragma unroll
        for (int off = 32; off >= 1; off >>= 1) {
            s1 += __shfl_xor(s1, off);
            s2 += __shfl_xor(s2, off);
        }
        float m   = s1 * (1.f / 128.f);
        float var = fmaxf(s2 * (1.f / 128.f) - m * m, 0.f);
        float isc = rsqrtf(var + 1e-5f);
        int row = base + rg * 8 + j;
        if (row < n) {
            size_t ro = (size_t)row * 128;
            float y0 = (acc0[j] - m) * isc * lgw0 + lgb0 + agts[ro + lc];
            float y1 = (acc1[j] - m) * isc * lgw1 + lgb1 + agts[ro + lc + 64];
            out[ro + lc]      = fmaxf(y0, 0.f);
            out[ro + lc + 64] = fmaxf(y1, 0.f);
        }
    }
}

// ---------------------------------------------------------------------------
extern "C" void kernel_launch(void* const* d_in, const int* in_sizes, int n_in,
                              void* d_out, int out_size, void* d_ws, size_t ws_size,
                              hipStream_t stream)
{
    const float* agts     = (const float*)d_in[0];
    const float* ctx      = (const float*)d_in[1];
    const float* agt_ctrs = (const float*)d_in[2];
    const float* ctx_ctrs = (const float*)d_in[3];
    const int*   hi       = (const int*)d_in[4];
    const int*   wi       = (const int*)d_in[5];
    const float* dist_w1  = (const float*)d_in[6];
    const float* dist_b1  = (const float*)d_in[7];
    const float* dist_w2  = (const float*)d_in[8];
    const float* dist_gw  = (const float*)d_in[9];
    const float* dist_gb  = (const float*)d_in[10];
    const float* q_w      = (const float*)d_in[11];
    const float* q_gw     = (const float*)d_in[12];
    const float* q_gb     = (const float*)d_in[13];
    const float* ctx_w1   = (const float*)d_in[14];
    const float* ctx_gw   = (const float*)d_in[15];
    const float* ctx_gb   = (const float*)d_in[16];
    const float* ctx_w2   = (const float*)d_in[17];
    const float* agt_w    = (const float*)d_in[18];
    const float* norm_w   = (const float*)d_in[19];
    const float* norm_b   = (const float*)d_in[20];
    const float* lin_w    = (const float*)d_in[21];
    const float* lin_gw   = (const float*)d_in[22];
    const float* lin_gb   = (const float*)d_in[23];

    const int N = in_sizes[0] / 128;
    const int E = in_sizes[4];
    float* out   = (float*)d_out;
    float* Q_all = (float*)d_ws;
    const int q_pre = (ws_size >= (size_t)N * 128 * sizeof(float)) ? 1 : 0;

    const int rowBlocks = (N + TILE_E - 1) / TILE_E;
    const int numTiles  = (E + TILE_E - 1) / TILE_E;

    // K1: Q_all = relu(gn(agts @ q_w))   (only if workspace fits)
    if (q_pre)
        rowgemm_kernel<<<rowBlocks, 256, 0, stream>>>(agts, q_w, q_gw, q_gb, Q_all, N, 1);
    // K0: acc = agts @ agt_w  (into d_out)
    rowgemm_kernel<<<rowBlocks, 256, 0, stream>>>(agts, agt_w, nullptr, nullptr, out, N, 0);
    // K2: fused edge pipeline + scatter-add into acc
    edge_kernel<<<numTiles, 256, 0, stream>>>(agt_ctrs, ctx_ctrs, hi, wi,
        q_pre ? Q_all : agts, ctx,
        dist_w1, dist_b1, dist_w2, dist_gw, dist_gb,
        q_w, q_gw, q_gb,
        ctx_w1, ctx_gw, ctx_gb, ctx_w2,
        out, E, numTiles, q_pre);
    // K3: final row-wise norms + residual (in-place on d_out)
    final_kernel<<<rowBlocks, 256, 0, stream>>>(agts, norm_w, norm_b,
        lin_w, lin_gw, lin_gb, out, N);
}

// Round 2
// 528.828 us; speedup vs baseline: 5.9857x; 5.9857x over previous
//
#include <hip/hip_runtime.h>
#include <hip/hip_bf16.h>

#define TILE_E 32
#define WSTRIDE 132   // fp32 fallback-path stride
#define SB 136        // bf16 tile stride (272 B, 16B-aligned, 2-way max on b128)
#define SF 132        // f32 Y stride (528 B, 16B-aligned)

typedef __attribute__((ext_vector_type(8))) short short8;
typedef __attribute__((ext_vector_type(4))) float f32x4;

__device__ __forceinline__ unsigned short f2bf(float f) {
    union { float f; unsigned u; } v; v.f = f;
    unsigned r = v.u + 0x7fff + ((v.u >> 16) & 1);   // RNE
    return (unsigned short)(r >> 16);
}

__device__ __forceinline__ f32x4 mfma16(short8 a, short8 b, f32x4 c) {
    return __builtin_amdgcn_mfma_f32_16x16x32_bf16(a, b, c, 0, 0, 0);
}

// Load B-fragments of a 128x128 (row-major, ld=128) weight matrix for this
// wave's 32 output cols into registers. frag (cb,kc): B[k][col],
// col = colbase + cb*16 + (lane&15), k = kc*32 + (lane>>4)*8 + j.
__device__ __forceinline__ void load_bfrags(const float* __restrict__ W,
                                            int colbase, int lane, short8 wB[2][4])
{
    const int c  = colbase + (lane & 15);
    const int k0 = ((lane >> 4) & 3) * 8;
#pragma unroll
    for (int cb = 0; cb < 2; ++cb)
#pragma unroll
    for (int kc = 0; kc < 4; ++kc) {
        const float* p = W + (size_t)(kc * 32 + k0) * 128 + c + cb * 16;
        short8 v;
#pragma unroll
        for (int j = 0; j < 8; ++j) v[j] = (short)f2bf(p[(size_t)j * 128]);
        wB[cb][kc] = v;
    }
}

// acc[rb][cb] += X(32x128 bf16 tile, stride SB) @ W(regs). 8 A-reads, 16 MFMA.
__device__ __forceinline__ void mfma_gemm32(const unsigned short* __restrict__ X,
                                            const short8 wB[2][4],
                                            f32x4 acc[2][2], int lane)
{
    const int r  = lane & 15;
    const int kg = (lane >> 4) & 3;
#pragma unroll
    for (int rb = 0; rb < 2; ++rb) {
        const unsigned short* xp = X + (rb * 16 + r) * SB + kg * 8;
#pragma unroll
        for (int kc = 0; kc < 4; ++kc) {
            short8 a = *(const short8*)(xp + kc * 32);
            acc[rb][0] = mfma16(a, wB[0][kc], acc[rb][0]);
            acc[rb][1] = mfma16(a, wB[1][kc], acc[rb][1]);
        }
    }
}

// ---------------------------------------------------------------------------
// KD: D_bf[e] = bf16( relu(gn( relu(dctr @ dist_w1 + b1) @ dist_w2 )) )
// ---------------------------------------------------------------------------
__global__ __launch_bounds__(256) void kd_kernel(
    const float* __restrict__ agt_ctrs, const float* __restrict__ ctx_ctrs,
    const int* __restrict__ hi, const int* __restrict__ wi,
    const float* __restrict__ dist_w1, const float* __restrict__ dist_b1,
    const float* __restrict__ dist_w2,
    const float* __restrict__ dist_gw, const float* __restrict__ dist_gb,
    unsigned short* __restrict__ Dout, int E, int numTiles)
{
    __shared__ __align__(16) unsigned short sH[32 * SB];
    __shared__ __align__(16) float sY[32 * SF];
    __shared__ float sGw[128], sGb[128];
    __shared__ float sDx[32], sDy[32];

    const int tid  = threadIdx.x;
    const int lane = tid & 63;
    const int wv   = tid >> 6;
    const int colbase = wv * 32;
    const int r8 = tid >> 3, c0 = (tid & 7) * 16;

    short8 wB[2][4];
    load_bfrags(dist_w2, colbase, lane, wB);

    float w1x[16], w1y[16], b1v[16];
#pragma unroll
    for (int i = 0; i < 16; ++i) {
        w1x[i] = dist_w1[c0 + i];
        w1y[i] = dist_w1[128 + c0 + i];
        b1v[i] = dist_b1[c0 + i];
    }
    if (tid < 128) { sGw[tid] = dist_gw[tid]; sGb[tid] = dist_gb[tid]; }

    for (int tile = blockIdx.x; tile < numTiles; tile += gridDim.x) {
        const int base = tile * 32;
        __syncthreads();
        if (tid < 32) {
            int e = base + tid; int h = 0, w = 0;
            if (e < E) { h = hi[e]; w = wi[e]; }
            sDx[tid] = agt_ctrs[2 * h]     - ctx_ctrs[2 * w];
            sDy[tid] = agt_ctrs[2 * h + 1] - ctx_ctrs[2 * w + 1];
        }
        __syncthreads();
        {   // h1 tile
            float dx = sDx[r8], dy = sDy[r8];
            unsigned short* dst = sH + r8 * SB + c0;
#pragma unroll
            for (int i = 0; i < 16; ++i) {
                float v = fmaxf(fmaf(dx, w1x[i], fmaf(dy, w1y[i], b1v[i])), 0.f);
                dst[i] = f2bf(v);
            }
        }
        __syncthreads();

        f32x4 acc[2][2] = {{{0,0,0,0},{0,0,0,0}},{{0,0,0,0},{0,0,0,0}}};
        mfma_gemm32(sH, wB, acc, lane);

        {   // acc -> sY (separate buffer; no sync needed before write)
            const int rq = (lane >> 4) & 3, cl = lane & 15;
#pragma unroll
            for (int rb = 0; rb < 2; ++rb)
#pragma unroll
            for (int cb = 0; cb < 2; ++cb)
#pragma unroll
            for (int q = 0; q < 4; ++q)
                sY[(rb * 16 + rq * 4 + q) * SF + colbase + cb * 16 + cl] = acc[rb][cb][q];
        }
        __syncthreads();
        {   // per-row GN + relu -> global bf16
            const float* yp = sY + r8 * SF + c0;
            float vals[16]; float s1 = 0.f, s2 = 0.f;
#pragma unroll
            for (int i = 0; i < 16; ++i) { float v = yp[i]; vals[i] = v; s1 += v; s2 += v * v; }
#pragma unroll
            for (int off = 4; off >= 1; off >>= 1) {
                s1 += __shfl_xor(s1, off);
                s2 += __shfl_xor(s2, off);
            }
            float m   = s1 * (1.f / 128.f);
            float var = fmaxf(s2 * (1.f / 128.f) - m * m, 0.f);
            float isc = rsqrtf(var + 1e-5f);
            int e = base + r8;
            if (e < E) {
                short8 o0, o1;
#pragma unroll
                for (int i = 0; i < 16; ++i) {
                    float y = fmaxf((vals[i] - m) * isc * sGw[c0 + i] + sGb[c0 + i], 0.f);
                    if (i < 8) o0[i] = (short)f2bf(y); else o1[i - 8] = (short)f2bf(y);
                }
                short8* gp = (short8*)(Dout + (size_t)e * 128 + c0);
                gp[0] = o0; gp[1] = o1;
            }
        }
    }
}

// ---------------------------------------------------------------------------
// KMS: m = relu(gn(d@W1d + q@W1q + c@W1c)); out[hi] += m @ ctx_w2
// Weights of all 4 matrices live in registers (128 VGPRs). Persistent blocks.
// ---------------------------------------------------------------------------
__global__ __launch_bounds__(256, 2) void kms_kernel(
    const int* __restrict__ hi, const int* __restrict__ wi,
    const unsigned short* __restrict__ Dbf,
    const float* __restrict__ Qall, const float* __restrict__ ctx,
    const float* __restrict__ ctx_w1,
    const float* __restrict__ ctx_gw, const float* __restrict__ ctx_gb,
    const float* __restrict__ ctx_w2,
    float* __restrict__ out, int E, int numTiles)
{
    __shared__ __align__(16) unsigned short sD[32 * SB];
    __shared__ __align__(16) unsigned short sQ[32 * SB];
    __shared__ __align__(16) unsigned short sC[32 * SB];
    __shared__ __align__(16) float sY[32 * SF];
    __shared__ float sGw[128], sGb[128];
    __shared__ int sHiA[32], sWiA[32];

    const int tid  = threadIdx.x;
    const int lane = tid & 63;
    const int wv   = tid >> 6;
    const int colbase = wv * 32;
    const int r8 = tid >> 3, c0 = (tid & 7) * 16;

    short8 wBd[2][4], wBq[2][4], wBc[2][4], wB2[2][4];
    load_bfrags(ctx_w1,               colbase, lane, wBd);
    load_bfrags(ctx_w1 + 128 * 128,   colbase, lane, wBq);
    load_bfrags(ctx_w1 + 2 * 128 * 128, colbase, lane, wBc);
    load_bfrags(ctx_w2,               colbase, lane, wB2);
    if (tid < 128) { sGw[tid] = ctx_gw[tid]; sGb[tid] = ctx_gb[tid]; }

    for (int tile = blockIdx.x; tile < numTiles; tile += gridDim.x) {
        const int base = tile * 32;
        __syncthreads();   // protects sD/sHiA vs previous iteration's GEMM2/atomics
        if (tid < 32) {
            int e = base + tid; int h = 0, w = 0;
            if (e < E) { h = hi[e]; w = wi[e]; }
            sHiA[tid] = h; sWiA[tid] = w;
        }
        __syncthreads();
        {   // stage d/q/c rows (thread: row r8, cols c0..c0+15)
            int e = base + r8; if (e >= E) e = E - 1;
            const short8* dp = (const short8*)(Dbf + (size_t)e * 128 + c0);
            short8* dd = (short8*)(sD + r8 * SB + c0);
            dd[0] = dp[0]; dd[1] = dp[1];

            const float* qs = Qall + (size_t)sHiA[r8] * 128 + c0;
            const float* cs = ctx  + (size_t)sWiA[r8] * 128 + c0;
            short8 q0, q1, c0v, c1v;
#pragma unroll
            for (int i = 0; i < 8; ++i) {
                q0[i]  = (short)f2bf(qs[i]);     q1[i]  = (short)f2bf(qs[i + 8]);
                c0v[i] = (short)f2bf(cs[i]);     c1v[i] = (short)f2bf(cs[i + 8]);
            }
            short8* qd = (short8*)(sQ + r8 * SB + c0);
            short8* cd = (short8*)(sC + r8 * SB + c0);
            qd[0] = q0; qd[1] = q1; cd[0] = c0v; cd[1] = c1v;
        }
        __syncthreads();

        f32x4 acc[2][2] = {{{0,0,0,0},{0,0,0,0}},{{0,0,0,0},{0,0,0,0}}};
        mfma_gemm32(sD, wBd, acc, lane);
        mfma_gemm32(sQ, wBq, acc, lane);
        mfma_gemm32(sC, wBc, acc, lane);

        {   // acc -> sY
            const int rq = (lane >> 4) & 3, cl = lane & 15;
#pragma unroll
            for (int rb = 0; rb < 2; ++rb)
#pragma unroll
            for (int cb = 0; cb < 2; ++cb)
#pragma unroll
            for (int q = 0; q < 4; ++q)
                sY[(rb * 16 + rq * 4 + q) * SF + colbase + cb * 16 + cl] = acc[rb][cb][q];
        }
        __syncthreads();   // sY complete; also all GEMM1 reads of sD done
        {   // GN + relu -> m (bf16) into sD (reuse)
            const float* yp = sY + r8 * SF + c0;
            float vals[16]; float s1 = 0.f, s2 = 0.f;
#pragma unroll
            for (int i = 0; i < 16; ++i) { float v = yp[i]; vals[i] = v; s1 += v; s2 += v * v; }
#pragma unroll
            for (int off = 4; off >= 1; off >>= 1) {
                s1 += __shfl_xor(s1, off);
                s2 += __shfl_xor(s2, off);
            }
            float m   = s1 * (1.f / 128.f);
            float var = fmaxf(s2 * (1.f / 128.f) - m * m, 0.f);
            float isc = rsqrtf(var + 1e-5f);
            unsigned short* dst = sD + r8 * SB + c0;
#pragma unroll
            for (int i = 0; i < 16; ++i) {
                float y = fmaxf((vals[i] - m) * isc * sGw[c0 + i] + sGb[c0 + i], 0.f);
                dst[i] = f2bf(y);
            }
        }
        __syncthreads();

        f32x4 a2[2][2] = {{{0,0,0,0},{0,0,0,0}},{{0,0,0,0},{0,0,0,0}}};
        mfma_gemm32(sD, wB2, a2, lane);
        {   // scatter-add
            const int rq = (lane >> 4) & 3, cl = lane & 15;
#pragma unroll
            for (int rb = 0; rb < 2; ++rb)
#pragma unroll
            for (int q = 0; q < 4; ++q) {
                int r = rb * 16 + rq * 4 + q;
                if (base + r < E) {
                    size_t ro = (size_t)sHiA[r] * 128 + colbase + cl;
                    atomicAdd(&out[ro],      a2[rb][0][q]);
                    atomicAdd(&out[ro + 16], a2[rb][1][q]);
                }
            }
        }
    }
}

// ---------------------------------------------------------------------------
// fp32 helper kernels (round-1, unchanged): rowgemm / edge fallback / final
// ---------------------------------------------------------------------------
__device__ __forceinline__ void gemm_tile(const float* __restrict__ sX,
                                          const float* __restrict__ sWT,
                                          int lc, int rg,
                                          float acc0[8], float acc1[8])
{
    const float* w0p = sWT + lc * WSTRIDE;
    const float* w1p = sWT + (lc + 64) * WSTRIDE;
    const float* xp  = sX + rg * 8 * WSTRIDE;
#pragma unroll 4
    for (int k = 0; k < 128; k += 4) {
        float4 w0 = *(const float4*)(w0p + k);
        float4 w1 = *(const float4*)(w1p + k);
#pragma unroll
        for (int j = 0; j < 8; ++j) {
            float4 x = *(const float4*)(xp + j * WSTRIDE + k);
            acc0[j] = fmaf(x.x, w0.x, acc0[j]);
            acc0[j] = fmaf(x.y, w0.y, acc0[j]);
            acc0[j] = fmaf(x.z, w0.z, acc0[j]);
            acc0[j] = fmaf(x.w, w0.w, acc0[j]);
            acc1[j] = fmaf(x.x, w1.x, acc1[j]);
            acc1[j] = fmaf(x.y, w1.y, acc1[j]);
            acc1[j] = fmaf(x.z, w1.z, acc1[j]);
            acc1[j] = fmaf(x.w, w1.w, acc1[j]);
        }
    }
}

__device__ __forceinline__ void stage_wt(const float* __restrict__ W,
                                         float* __restrict__ sWT, int tid)
{
    const int c  = tid & 127;
    const int k0 = tid >> 7;
    float*       dst = sWT + c * WSTRIDE + k0;
    const float* src = W + tid;
    float v[16];
#pragma unroll
    for (int p = 0; p < 4; ++p) {
#pragma unroll
        for (int i = 0; i < 16; ++i) v[i] = src[(p * 16 + i) * 256];
#pragma unroll
        for (int i = 0; i < 16; ++i) dst[(p * 16 + i) * 2] = v[i];
    }
}

__device__ __forceinline__ void gn_rows_lds(const float acc0[8], const float acc1[8],
                                            float gw0, float gw1, float gb0, float gb1,
                                            bool relu, float* __restrict__ dst,
                                            int lc, int rg)
{
#pragma unroll
    for (int j = 0; j < 8; ++j) {
        float s1 = acc0[j] + acc1[j];
        float s2 = acc0[j] * acc0[j] + acc1[j] * acc1[j];
#pragma unroll
        for (int off = 32; off >= 1; off >>= 1) {
            s1 += __shfl_xor(s1, off);
            s2 += __shfl_xor(s2, off);
        }
        float m   = s1 * (1.f / 128.f);
        float var = fmaxf(s2 * (1.f / 128.f) - m * m, 0.f);
        float isc = rsqrtf(var + 1e-5f);
        float y0  = (acc0[j] - m) * isc * gw0 + gb0;
        float y1  = (acc1[j] - m) * isc * gw1 + gb1;
        if (relu) { y0 = fmaxf(y0, 0.f); y1 = fmaxf(y1, 0.f); }
        int r = rg * 8 + j;
        dst[r * WSTRIDE + lc]      = y0;
        dst[r * WSTRIDE + lc + 64] = y1;
    }
}

__global__ __launch_bounds__(256) void rowgemm_kernel(
    const float* __restrict__ X, const float* __restrict__ W,
    const float* __restrict__ gw, const float* __restrict__ gb,
    float* __restrict__ Y, int n, int gn_relu)
{
    __shared__ float sWT[128 * WSTRIDE];
    __shared__ float sX[TILE_E * WSTRIDE];
    const int tid  = threadIdx.x;
    const int base = blockIdx.x * TILE_E;

    {
        int r = tid >> 3, c0 = (tid & 7) * 16;
        int row = base + r;
        if (row < n) {
            const float* src = X + (size_t)row * 128 + c0;
            float*       dst = sX + r * WSTRIDE + c0;
#pragma unroll
            for (int i = 0; i < 4; ++i)
                *(float4*)(dst + i * 4) = *(const float4*)(src + i * 4);
        }
    }
    stage_wt(W, sWT, tid);
    __syncthreads();

    const int lc = tid & 63, rg = tid >> 6;
    float acc0[8] = {0,0,0,0,0,0,0,0}, acc1[8] = {0,0,0,0,0,0,0,0};
    gemm_tile(sX, sWT, lc, rg, acc0, acc1);

    if (gn_relu) {
        float gw0 = gw[lc], gw1 = gw[lc + 64], gb0 = gb[lc], gb1 = gb[lc + 64];
#pragma unroll
        for (int j = 0; j < 8; ++j) {
            float s1 = acc0[j] + acc1[j];
            float s2 = acc0[j] * acc0[j] + acc1[j] * acc1[j];
#pragma unroll
            for (int off = 32; off >= 1; off >>= 1) {
                s1 += __shfl_xor(s1, off);
                s2 += __shfl_xor(s2, off);
            }
            float m   = s1 * (1.f / 128.f);
            float var = fmaxf(s2 * (1.f / 128.f) - m * m, 0.f);
            float isc = rsqrtf(var + 1e-5f);
            int row = base + rg * 8 + j;
            if (row < n) {
                float y0 = fmaxf((acc0[j] - m) * isc * gw0 + gb0, 0.f);
                float y1 = fmaxf((acc1[j] - m) * isc * gw1 + gb1, 0.f);
                Y[(size_t)row * 128 + lc]      = y0;
                Y[(size_t)row * 128 + lc + 64] = y1;
            }
        }
    } else {
#pragma unroll
        for (int j = 0; j < 8; ++j) {
            int row = base + rg * 8 + j;
            if (row < n) {
                Y[(size_t)row * 128 + lc]      = acc0[j];
                Y[(size_t)row * 128 + lc + 64] = acc1[j];
            }
        }
    }
}

__global__ __launch_bounds__(256) void edge_kernel(
    const float* __restrict__ agt_ctrs, const float* __restrict__ ctx_ctrs,
    const int* __restrict__ hi, const int* __restrict__ wi,
    const float* __restrict__ qsrc, const float* __restrict__ ctx,
    const float* __restrict__ dist_w1, const float* __restrict__ dist_b1,
    const float* __restrict__ dist_w2,
    const float* __restrict__ dist_gw, const float* __restrict__ dist_gb,
    const float* __restrict__ q_w,
    const float* __restrict__ q_gw, const float* __restrict__ q_gb,
    const float* __restrict__ ctx_w1,
    const float* __restrict__ ctx_gw, const float* __restrict__ ctx_gb,
    const float* __restrict__ ctx_w2,
    float* __restrict__ out, int E, int numTiles, int q_pre)
{
    __shared__ float sWT[128 * WSTRIDE];
    __shared__ float sH[TILE_E * WSTRIDE];
    __shared__ float sD2[TILE_E * WSTRIDE];
    __shared__ float sQ2[TILE_E * WSTRIDE];
    __shared__ float sC2[TILE_E * WSTRIDE];
    __shared__ int   sHi[TILE_E];
    __shared__ int   sWiB[TILE_E];
    __shared__ float sDx[TILE_E], sDy[TILE_E];

    const int tid = threadIdx.x;
    const int lc = tid & 63, rg = tid >> 6;

    const float dgw0 = dist_gw[lc], dgw1 = dist_gw[lc + 64];
    const float dgb0 = dist_gb[lc], dgb1 = dist_gb[lc + 64];
    const float cgw0 = ctx_gw[lc],  cgw1 = ctx_gw[lc + 64];
    const float cgb0 = ctx_gb[lc],  cgb1 = ctx_gb[lc + 64];
    float qgw0 = 0, qgw1 = 0, qgb0 = 0, qgb1 = 0;
    if (!q_pre) { qgw0 = q_gw[lc]; qgw1 = q_gw[lc + 64]; qgb0 = q_gb[lc]; qgb1 = q_gb[lc + 64]; }
    const int   hc  = tid & 127;
    const int   hrg = tid >> 7;
    const float w1x = dist_w1[hc], w1y = dist_w1[128 + hc], b1c = dist_b1[hc];

    for (int tile = blockIdx.x; tile < numTiles; tile += gridDim.x) {
        const int base = tile * TILE_E;
        __syncthreads();
        if (tid < TILE_E) {
            int e = base + tid;
            int h = 0, w = 0;
            if (e < E) { h = hi[e]; w = wi[e]; }
            sHi[tid]  = h;
            sWiB[tid] = w;
            sDx[tid] = agt_ctrs[2 * h]     - ctx_ctrs[2 * w];
            sDy[tid] = agt_ctrs[2 * h + 1] - ctx_ctrs[2 * w + 1];
        }
        __syncthreads();

        {
            int r = tid >> 3, c0 = (tid & 7) * 16;
            int h = sHi[r], w = sWiB[r];
            const float* qs = qsrc + (size_t)h * 128 + c0;
            const float* cs = ctx  + (size_t)w * 128 + c0;
            float* qd = sQ2 + r * WSTRIDE + c0;
            float* cd = sC2 + r * WSTRIDE + c0;
#pragma unroll
            for (int i = 0; i < 4; ++i) {
                *(float4*)(qd + i * 4) = *(const float4*)(qs + i * 4);
                *(float4*)(cd + i * 4) = *(const float4*)(cs + i * 4);
            }
        }
        {
#pragma unroll
            for (int j = 0; j < 16; ++j) {
                int r = hrg * 16 + j;
                float v = fmaf(sDx[r], w1x, fmaf(sDy[r], w1y, b1c));
                sH[r * WSTRIDE + hc] = fmaxf(v, 0.f);
            }
        }

        if (!q_pre) {
            __syncthreads();
            stage_wt(q_w, sWT, tid);
            __syncthreads();
            float a0[8] = {0,0,0,0,0,0,0,0}, a1[8] = {0,0,0,0,0,0,0,0};
            gemm_tile(sQ2, sWT, lc, rg, a0, a1);
            __syncthreads();
            gn_rows_lds(a0, a1, qgw0, qgw1, qgb0, qgb1, true, sQ2, lc, rg);
        }

        __syncthreads();
        stage_wt(dist_w2, sWT, tid);
        __syncthreads();
        {
            float a0[8] = {0,0,0,0,0,0,0,0}, a1[8] = {0,0,0,0,0,0,0,0};
            gemm_tile(sH, sWT, lc, rg, a0, a1);
            gn_rows_lds(a0, a1, dgw0, dgw1, dgb0, dgb1, true, sD2, lc, rg);
        }

        float m0[8] = {0,0,0,0,0,0,0,0}, m1[8] = {0,0,0,0,0,0,0,0};
        __syncthreads();
        stage_wt(ctx_w1, sWT, tid);
        __syncthreads();
        gemm_tile(sD2, sWT, lc, rg, m0, m1);
        __syncthreads();
        stage_wt(ctx_w1 + 128 * 128, sWT, tid);
        __syncthreads();
        gemm_tile(sQ2, sWT, lc, rg, m0, m1);
        __syncthreads();
        stage_wt(ctx_w1 + 2 * 128 * 128, sWT, tid);
        __syncthreads();
        gemm_tile(sC2, sWT, lc, rg, m0, m1);
        gn_rows_lds(m0, m1, cgw0, cgw1, cgb0, cgb1, true, sH, lc, rg);

        __syncthreads();
        stage_wt(ctx_w2, sWT, tid);
        __syncthreads();
        {
            float a0[8] = {0,0,0,0,0,0,0,0}, a1[8] = {0,0,0,0,0,0,0,0};
            gemm_tile(sH, sWT, lc, rg, a0, a1);
#pragma unroll
            for (int j = 0; j < 8; ++j) {
                int r = rg * 8 + j;
                int e = base + r;
                if (e < E) {
                    int h = sHi[r];
                    atomicAdd(&out[(size_t)h * 128 + lc],      a0[j]);
                    atomicAdd(&out[(size_t)h * 128 + lc + 64], a1[j]);
                }
            }
        }
    }
}

__global__ __launch_bounds__(256) void final_kernel(
    const float* __restrict__ agts,
    const float* __restrict__ norm_w, const float* __restrict__ norm_b,
    const float* __restrict__ lin_w,
    const float* __restrict__ lin_gw, const float* __restrict__ lin_gb,
    float* __restrict__ out, int n)
{
    __shared__ float sWT[128 * WSTRIDE];
    __shared__ float sX[TILE_E * WSTRIDE];
    const int tid  = threadIdx.x;
    const int base = blockIdx.x * TILE_E;

    {
        int r = tid >> 3, c0 = (tid & 7) * 16;
        int row = base + r;
        if (row < n) {
            const float* src = out + (size_t)row * 128 + c0;
            float vals[16];
            float s1 = 0.f, s2 = 0.f;
#pragma unroll
            for (int i = 0; i < 16; ++i) {
                float v = src[i];
                vals[i] = v; s1 += v; s2 += v * v;
            }
#pragma unroll
            for (int off = 4; off >= 1; off >>= 1) {
                s1 += __shfl_xor(s1, off);
                s2 += __shfl_xor(s2, off);
            }
            float m   = s1 * (1.f / 128.f);
            float var = fmaxf(s2 * (1.f / 128.f) - m * m, 0.f);
            float isc = rsqrtf(var + 1e-5f);
            float* dst = sX + r * WSTRIDE + c0;
#pragma unroll
            for (int i = 0; i < 16; ++i) {
                int c = c0 + i;
                float y = (vals[i] - m) * isc * norm_w[c] + norm_b[c];
                dst[i] = fmaxf(y, 0.f);
            }
        }
    }
    stage_wt(lin_w, sWT, tid);
    __syncthreads();

    const int lc = tid & 63, rg = tid >> 6;
    float acc0[8] = {0,0,0,0,0,0,0,0}, acc1[8] = {0,0,0,0,0,0,0,0};
    gemm_tile(sX, sWT, lc, rg, acc0, acc1);

    const float lgw0 = lin_gw[lc], lgw1 = lin_gw[lc + 64];
    const float lgb0 = lin_gb[lc], lgb1 = lin_gb[lc + 64];
#pragma unroll
    for (int j = 0; j < 8; ++j) {
        float s1 = acc0[j] + acc1[j];
        float s2 = acc0[j] * acc0[j] + acc1[j] * acc1[j];
#pragma unroll
        for (int off = 32; off >= 1; off >>= 1) {
            s1 += __shfl_xor(s1, off);
            s2 += __shfl_xor(s2, off);
        }
        float m   = s1 * (1.f / 128.f);
        float var = fmaxf(s2 * (1.f / 128.f) - m * m, 0.f);
        float isc = rsqrtf(var + 1e-5f);
        int row = base + rg * 8 + j;
        if (row < n) {
            size_t ro = (size_t)row * 128;
            float y0 = (acc0[j] - m) * isc * lgw0 + lgb0 + agts[ro + lc];
            float y1 = (acc1[j] - m) * isc * lgw1 + lgb1 + agts[ro + lc + 64];
            out[ro + lc]      = fmaxf(y0, 0.f);
            out[ro + lc + 64] = fmaxf(y1, 0.f);
        }
    }
}

// ---------------------------------------------------------------------------
extern "C" void kernel_launch(void* const* d_in, const int* in_sizes, int n_in,
                              void* d_out, int out_size, void* d_ws, size_t ws_size,
                              hipStream_t stream)
{
    const float* agts     = (const float*)d_in[0];
    const float* ctx      = (const float*)d_in[1];
    const float* agt_ctrs = (const float*)d_in[2];
    const float* ctx_ctrs = (const float*)d_in[3];
    const int*   hi       = (const int*)d_in[4];
    const int*   wi       = (const int*)d_in[5];
    const float* dist_w1  = (const float*)d_in[6];
    const float* dist_b1  = (const float*)d_in[7];
    const float* dist_w2  = (const float*)d_in[8];
    const float* dist_gw  = (const float*)d_in[9];
    const float* dist_gb  = (const float*)d_in[10];
    const float* q_w      = (const float*)d_in[11];
    const float* q_gw     = (const float*)d_in[12];
    const float* q_gb     = (const float*)d_in[13];
    const float* ctx_w1   = (const float*)d_in[14];
    const float* ctx_gw   = (const float*)d_in[15];
    const float* ctx_gb   = (const float*)d_in[16];
    const float* ctx_w2   = (const float*)d_in[17];
    const float* agt_w    = (const float*)d_in[18];
    const float* norm_w   = (const float*)d_in[19];
    const float* norm_b   = (const float*)d_in[20];
    const float* lin_w    = (const float*)d_in[21];
    const float* lin_gw   = (const float*)d_in[22];
    const float* lin_gb   = (const float*)d_in[23];

    const int N = in_sizes[0] / 128;
    const int E = in_sizes[4];
    float* out = (float*)d_out;

    const int rowBlocks = (N + TILE_E - 1) / TILE_E;
    const int numTiles  = (E + TILE_E - 1) / TILE_E;

    const size_t needD = (size_t)E * 128 * sizeof(unsigned short);
    const size_t needQ = (size_t)N * 128 * sizeof(float);

    if (ws_size >= needD + needQ) {
        unsigned short* Dbf  = (unsigned short*)d_ws;
        float*          Qall = (float*)((char*)d_ws + needD);

        // KQ: Q_all = relu(gn(agts @ q_w))  (fp32)
        rowgemm_kernel<<<rowBlocks, 256, 0, stream>>>(agts, q_w, q_gw, q_gb, Qall, N, 1);
        // KA: out = agts @ agt_w
        rowgemm_kernel<<<rowBlocks, 256, 0, stream>>>(agts, agt_w, nullptr, nullptr, out, N, 0);
        // KD: dist path -> D_bf
        int gridD = numTiles < 2048 ? numTiles : 2048;
        kd_kernel<<<gridD, 256, 0, stream>>>(agt_ctrs, ctx_ctrs, hi, wi,
            dist_w1, dist_b1, dist_w2, dist_gw, dist_gb, Dbf, E, numTiles);
        // KMS: message GEMMs + scatter-add
        int gridM = numTiles < 512 ? numTiles : 512;
        kms_kernel<<<gridM, 256, 0, stream>>>(hi, wi, Dbf, Qall, ctx,
            ctx_w1, ctx_gw, ctx_gb, ctx_w2, out, E, numTiles);
        // KF: final row-wise
        final_kernel<<<rowBlocks, 256, 0, stream>>>(agts, norm_w, norm_b,
            lin_w, lin_gw, lin_gb, out, N);
    } else {
        // fallback: round-1 fp32 path
        float* Qall = (float*)d_ws;
        const int q_pre = (ws_size >= needQ) ? 1 : 0;
        if (q_pre)
            rowgemm_kernel<<<rowBlocks, 256, 0, stream>>>(agts, q_w, q_gw, q_gb, Qall, N, 1);
        rowgemm_kernel<<<rowBlocks, 256, 0, stream>>>(agts, agt_w, nullptr, nullptr, out, N, 0);
        int gridE = numTiles < 8192 ? numTiles : 8192;
        edge_kernel<<<gridE, 256, 0, stream>>>(agt_ctrs, ctx_ctrs, hi, wi,
            q_pre ? Qall : agts, ctx,
            dist_w1, dist_b1, dist_w2, dist_gw, dist_gb,
            q_w, q_gw, q_gb,
            ctx_w1, ctx_gw, ctx_gb, ctx_w2,
            out, E, numTiles, q_pre);
        final_kernel<<<rowBlocks, 256, 0, stream>>>(agts, norm_w, norm_b,
            lin_w, lin_gw, lin_gb, out, N);
    }
}

// Round 3
// 481.284 us; speedup vs baseline: 6.5770x; 1.0988x over previous
//
#include <hip/hip_runtime.h>
#include <hip/hip_bf16.h>

#define TILE_E 32
#define WSTRIDE 132   // fp32 fallback-path stride
#define SB 136        // bf16 tile stride (272 B, 16B-aligned)
#define SF 132        // f32 Y stride (528 B, 16B-aligned)

typedef __attribute__((ext_vector_type(8))) short short8;
typedef __attribute__((ext_vector_type(4))) float f32x4;

__device__ __forceinline__ unsigned short f2bf(float f) {
    union { float f; unsigned u; } v; v.f = f;
    unsigned r = v.u + 0x7fff + ((v.u >> 16) & 1);   // RNE
    return (unsigned short)(r >> 16);
}

__device__ __forceinline__ f32x4 mfma16(short8 a, short8 b, f32x4 c) {
    return __builtin_amdgcn_mfma_f32_16x16x32_bf16(a, b, c, 0, 0, 0);
}

// B-fragments of a 128x128 row-major weight for this wave's 32 output cols.
// frag (cb,kc): B[k][col], col = colbase + cb*16 + (lane&15), k = kc*32 + (lane>>4)*8 + j.
__device__ __forceinline__ void load_bfrags(const float* __restrict__ W,
                                            int colbase, int lane, short8 wB[2][4])
{
    const int c  = colbase + (lane & 15);
    const int k0 = ((lane >> 4) & 3) * 8;
#pragma unroll
    for (int cb = 0; cb < 2; ++cb)
#pragma unroll
    for (int kc = 0; kc < 4; ++kc) {
        const float* p = W + (size_t)(kc * 32 + k0) * 128 + c + cb * 16;
        short8 v;
#pragma unroll
        for (int j = 0; j < 8; ++j) v[j] = (short)f2bf(p[(size_t)j * 128]);
        wB[cb][kc] = v;
    }
}

// acc[rb][cb] += X(32x128 bf16 tile, stride SB) @ W(regs). 8 A-reads, 16 MFMA.
__device__ __forceinline__ void mfma_gemm32(const unsigned short* __restrict__ X,
                                            const short8 wB[2][4],
                                            f32x4 acc[2][2], int lane)
{
    const int r  = lane & 15;
    const int kg = (lane >> 4) & 3;
#pragma unroll
    for (int rb = 0; rb < 2; ++rb) {
        const unsigned short* xp = X + (rb * 16 + r) * SB + kg * 8;
#pragma unroll
        for (int kc = 0; kc < 4; ++kc) {
            short8 a = *(const short8*)(xp + kc * 32);
            acc[rb][0] = mfma16(a, wB[0][kc], acc[rb][0]);
            acc[rb][1] = mfma16(a, wB[1][kc], acc[rb][1]);
        }
    }
}

// Per-row GN over one 32-row f32 tile in sY (8 threads/row), optional relu,
// write bf16 into dst tile (stride SB).
__device__ __forceinline__ void gn_row_to_bf16(const float* __restrict__ sY,
                                               const float* __restrict__ gw,
                                               const float* __restrict__ gb,
                                               unsigned short* __restrict__ dst,
                                               int r8, int c0)
{
    const float* yp = sY + r8 * SF + c0;
    float vals[16]; float s1 = 0.f, s2 = 0.f;
#pragma unroll
    for (int i = 0; i < 16; ++i) { float v = yp[i]; vals[i] = v; s1 += v; s2 += v * v; }
#pragma unroll
    for (int off = 4; off >= 1; off >>= 1) {
        s1 += __shfl_xor(s1, off);
        s2 += __shfl_xor(s2, off);
    }
    float m   = s1 * (1.f / 128.f);
    float var = fmaxf(s2 * (1.f / 128.f) - m * m, 0.f);
    float isc = rsqrtf(var + 1e-5f);
    unsigned short* dp = dst + r8 * SB + c0;
#pragma unroll
    for (int i = 0; i < 16; ++i) {
        float y = fmaxf((vals[i] - m) * isc * gw[c0 + i] + gb[c0 + i], 0.f);
        dp[i] = f2bf(y);
    }
}

// ---------------------------------------------------------------------------
// KQ: qm_perm = (relu(gn(agts @ q_w))) @ W1q   (fp32, permuted col layout)
// perm: addr(row, wv, cl, cb) = row*128 + wv*32 + cl*2 + cb  holds col wv*32+cb*16+cl
// ---------------------------------------------------------------------------
__global__ __launch_bounds__(256) void kq_kernel(
    const float* __restrict__ agts,
    const float* __restrict__ q_w,
    const float* __restrict__ q_gw, const float* __restrict__ q_gb,
    const float* __restrict__ w1q,
    float* __restrict__ qm, int N)
{
    __shared__ __align__(16) unsigned short sX[32 * SB];
    __shared__ __align__(16) float sY[32 * SF];
    __shared__ float sGw[128], sGb[128];

    const int tid  = threadIdx.x;
    const int lane = tid & 63;
    const int wv   = tid >> 6;
    const int colbase = wv * 32;
    const int r8 = tid >> 3, c0 = (tid & 7) * 16;
    const int cl = lane & 15, rq = lane >> 4;

    short8 wBq[2][4], wB1[2][4];
    load_bfrags(q_w, colbase, lane, wBq);
    load_bfrags(w1q, colbase, lane, wB1);
    if (tid < 128) { sGw[tid] = q_gw[tid]; sGb[tid] = q_gb[tid]; }

    const int base = blockIdx.x * 32;
    {   // stage agts rows -> bf16
        int row = base + r8; if (row >= N) row = N - 1;
        const float* src = agts + (size_t)row * 128 + c0;
        short8 v0, v1;
#pragma unroll
        for (int i = 0; i < 8; ++i) { v0[i] = (short)f2bf(src[i]); v1[i] = (short)f2bf(src[i + 8]); }
        short8* dp = (short8*)(sX + r8 * SB + c0);
        dp[0] = v0; dp[1] = v1;
    }
    __syncthreads();

    f32x4 acc[2][2] = {{{0,0,0,0},{0,0,0,0}},{{0,0,0,0},{0,0,0,0}}};
    mfma_gemm32(sX, wBq, acc, lane);
    {
#pragma unroll
        for (int rb = 0; rb < 2; ++rb)
#pragma unroll
        for (int cb = 0; cb < 2; ++cb)
#pragma unroll
        for (int q = 0; q < 4; ++q)
            sY[(rb * 16 + rq * 4 + q) * SF + colbase + cb * 16 + cl] = acc[rb][cb][q];
    }
    __syncthreads();            // sY ready AND all waves done reading sX
    gn_row_to_bf16(sY, sGw, sGb, sX, r8, c0);   // q bf16 back into sX
    __syncthreads();

    f32x4 a2[2][2] = {{{0,0,0,0},{0,0,0,0}},{{0,0,0,0},{0,0,0,0}}};
    mfma_gemm32(sX, wB1, a2, lane);
#pragma unroll
    for (int rb = 0; rb < 2; ++rb)
#pragma unroll
    for (int q = 0; q < 4; ++q) {
        int row = base + rb * 16 + rq * 4 + q;
        if (row < N) {
            float2 v = make_float2(a2[rb][0][q], a2[rb][1][q]);
            *(float2*)(qm + (size_t)row * 128 + colbase + cl * 2) = v;
        }
    }
}

// ---------------------------------------------------------------------------
// KC: cm_perm = ctx @ W1c   (fp32, same permuted layout)
// ---------------------------------------------------------------------------
__global__ __launch_bounds__(256) void kc_kernel(
    const float* __restrict__ ctx,
    const float* __restrict__ w1c,
    float* __restrict__ cm, int N)
{
    __shared__ __align__(16) unsigned short sX[32 * SB];

    const int tid  = threadIdx.x;
    const int lane = tid & 63;
    const int wv   = tid >> 6;
    const int colbase = wv * 32;
    const int r8 = tid >> 3, c0 = (tid & 7) * 16;
    const int cl = lane & 15, rq = lane >> 4;

    short8 wB[2][4];
    load_bfrags(w1c, colbase, lane, wB);

    const int base = blockIdx.x * 32;
    {
        int row = base + r8; if (row >= N) row = N - 1;
        const float* src = ctx + (size_t)row * 128 + c0;
        short8 v0, v1;
#pragma unroll
        for (int i = 0; i < 8; ++i) { v0[i] = (short)f2bf(src[i]); v1[i] = (short)f2bf(src[i + 8]); }
        short8* dp = (short8*)(sX + r8 * SB + c0);
        dp[0] = v0; dp[1] = v1;
    }
    __syncthreads();

    f32x4 acc[2][2] = {{{0,0,0,0},{0,0,0,0}},{{0,0,0,0},{0,0,0,0}}};
    mfma_gemm32(sX, wB, acc, lane);
#pragma unroll
    for (int rb = 0; rb < 2; ++rb)
#pragma unroll
    for (int q = 0; q < 4; ++q) {
        int row = base + rb * 16 + rq * 4 + q;
        if (row < N) {
            float2 v = make_float2(acc[rb][0][q], acc[rb][1][q]);
            *(float2*)(cm + (size_t)row * 128 + colbase + cl * 2) = v;
        }
    }
}

// ---------------------------------------------------------------------------
// EDGE FUSED: dist MLP + (d@W1d + gather(qm)+gather(cm)) GN + @ctx_w2 + scatter
// ---------------------------------------------------------------------------
__global__ __launch_bounds__(256, 3) void edge_fused_kernel(
    const float* __restrict__ agt_ctrs, const float* __restrict__ ctx_ctrs,
    const int* __restrict__ hi, const int* __restrict__ wi,
    const float* __restrict__ dist_w1, const float* __restrict__ dist_b1,
    const float* __restrict__ dist_w2,
    const float* __restrict__ dist_gw, const float* __restrict__ dist_gb,
    const float* __restrict__ w1d,
    const float* __restrict__ ctx_gw, const float* __restrict__ ctx_gb,
    const float* __restrict__ ctx_w2,
    const float* __restrict__ qm, const float* __restrict__ cm,
    float* __restrict__ out, int E, int numTiles)
{
    __shared__ __align__(16) unsigned short sH[32 * SB];   // region A: h1, later m
    __shared__ __align__(16) unsigned short sD[32 * SB];   // region B: d
    __shared__ __align__(16) float sY[32 * SF];            // region C
    __shared__ float sW1[3][128];
    __shared__ float sDGw[128], sDGb[128], sCGw[128], sCGb[128];
    __shared__ int sHiA[32], sWiA[32];
    __shared__ float sDx[32], sDy[32];

    const int tid  = threadIdx.x;
    const int lane = tid & 63;
    const int wv   = tid >> 6;
    const int colbase = wv * 32;
    const int r8 = tid >> 3, c0 = (tid & 7) * 16;
    const int cl = lane & 15, rq = lane >> 4;

    short8 wBh[2][4], wBd[2][4], wB2[2][4];
    load_bfrags(dist_w2, colbase, lane, wBh);
    load_bfrags(w1d,     colbase, lane, wBd);
    load_bfrags(ctx_w2,  colbase, lane, wB2);
    if (tid < 128) {
        sW1[0][tid] = dist_w1[tid];
        sW1[1][tid] = dist_w1[128 + tid];
        sW1[2][tid] = dist_b1[tid];
        sDGw[tid] = dist_gw[tid]; sDGb[tid] = dist_gb[tid];
        sCGw[tid] = ctx_gw[tid];  sCGb[tid] = ctx_gb[tid];
    }

    for (int tile = blockIdx.x; tile < numTiles; tile += gridDim.x) {
        const int base = tile * 32;
        __syncthreads();                                   // (a)
        if (tid < 32) {
            int e = base + tid; int h = 0, w = 0;
            if (e < E) { h = hi[e]; w = wi[e]; }
            sHiA[tid] = h; sWiA[tid] = w;
            sDx[tid] = agt_ctrs[2 * h]     - ctx_ctrs[2 * w];
            sDy[tid] = agt_ctrs[2 * h + 1] - ctx_ctrs[2 * w + 1];
        }
        __syncthreads();                                   // (b)

        // early gathers of precomputed qm/cm chunks (permuted: float2 = both cb)
        float2 gq[2][4], gc[2][4];
#pragma unroll
        for (int rb = 0; rb < 2; ++rb)
#pragma unroll
        for (int q = 0; q < 4; ++q) {
            int r = rb * 16 + rq * 4 + q;
            gq[rb][q] = *(const float2*)(qm + (size_t)sHiA[r] * 128 + colbase + cl * 2);
            gc[rb][q] = *(const float2*)(cm + (size_t)sWiA[r] * 128 + colbase + cl * 2);
        }

        {   // h1 = relu(dctr @ dist_w1 + b1) -> sH bf16
            float dx = sDx[r8], dy = sDy[r8];
            unsigned short* dst = sH + r8 * SB + c0;
#pragma unroll
            for (int i = 0; i < 16; ++i) {
                int c = c0 + i;
                float v = fmaf(dx, sW1[0][c], fmaf(dy, sW1[1][c], sW1[2][c]));
                dst[i] = f2bf(fmaxf(v, 0.f));
            }
        }
        __syncthreads();                                   // (c)

        f32x4 acc[2][2] = {{{0,0,0,0},{0,0,0,0}},{{0,0,0,0},{0,0,0,0}}};
        mfma_gemm32(sH, wBh, acc, lane);
        {
#pragma unroll
            for (int rb = 0; rb < 2; ++rb)
#pragma unroll
            for (int cb = 0; cb < 2; ++cb)
#pragma unroll
            for (int q = 0; q < 4; ++q)
                sY[(rb * 16 + rq * 4 + q) * SF + colbase + cb * 16 + cl] = acc[rb][cb][q];
        }
        __syncthreads();                                   // (d) sY ready; sH reads done
        gn_row_to_bf16(sY, sDGw, sDGb, sD, r8, c0);        // d -> sD
        __syncthreads();                                   // (e)

        f32x4 a2[2][2];
#pragma unroll
        for (int rb = 0; rb < 2; ++rb)
#pragma unroll
        for (int q = 0; q < 4; ++q) {
            a2[rb][0][q] = gq[rb][q].x + gc[rb][q].x;
            a2[rb][1][q] = gq[rb][q].y + gc[rb][q].y;
        }
        mfma_gemm32(sD, wBd, a2, lane);
        {
#pragma unroll
            for (int rb = 0; rb < 2; ++rb)
#pragma unroll
            for (int cb = 0; cb < 2; ++cb)
#pragma unroll
            for (int q = 0; q < 4; ++q)
                sY[(rb * 16 + rq * 4 + q) * SF + colbase + cb * 16 + cl] = a2[rb][cb][q];
        }
        __syncthreads();                                   // (f)
        gn_row_to_bf16(sY, sCGw, sCGb, sH, r8, c0);        // m -> sH (region A reuse)
        __syncthreads();                                   // (g)

        f32x4 a3[2][2] = {{{0,0,0,0},{0,0,0,0}},{{0,0,0,0},{0,0,0,0}}};
        mfma_gemm32(sH, wB2, a3, lane);
#pragma unroll
        for (int rb = 0; rb < 2; ++rb)
#pragma unroll
        for (int q = 0; q < 4; ++q) {
            int r = rb * 16 + rq * 4 + q;
            if (base + r < E) {
                size_t ro = (size_t)sHiA[r] * 128 + colbase + cl;
                atomicAdd(&out[ro],      a3[rb][0][q]);
                atomicAdd(&out[ro + 16], a3[rb][1][q]);
            }
        }
    }
}

// ---------------------------------------------------------------------------
// fp32 helpers (KA base GEMM, final, and full fp32 fallback path)
// ---------------------------------------------------------------------------
__device__ __forceinline__ void gemm_tile(const float* __restrict__ sX,
                                          const float* __restrict__ sWT,
                                          int lc, int rg,
                                          float acc0[8], float acc1[8])
{
    const float* w0p = sWT + lc * WSTRIDE;
    const float* w1p = sWT + (lc + 64) * WSTRIDE;
    const float* xp  = sX + rg * 8 * WSTRIDE;
#pragma unroll 4
    for (int k = 0; k < 128; k += 4) {
        float4 w0 = *(const float4*)(w0p + k);
        float4 w1 = *(const float4*)(w1p + k);
#pragma unroll
        for (int j = 0; j < 8; ++j) {
            float4 x = *(const float4*)(xp + j * WSTRIDE + k);
            acc0[j] = fmaf(x.x, w0.x, acc0[j]);
            acc0[j] = fmaf(x.y, w0.y, acc0[j]);
            acc0[j] = fmaf(x.z, w0.z, acc0[j]);
            acc0[j] = fmaf(x.w, w0.w, acc0[j]);
            acc1[j] = fmaf(x.x, w1.x, acc1[j]);
            acc1[j] = fmaf(x.y, w1.y, acc1[j]);
            acc1[j] = fmaf(x.z, w1.z, acc1[j]);
            acc1[j] = fmaf(x.w, w1.w, acc1[j]);
        }
    }
}

__device__ __forceinline__ void stage_wt(const float* __restrict__ W,
                                         float* __restrict__ sWT, int tid)
{
    const int c  = tid & 127;
    const int k0 = tid >> 7;
    float*       dst = sWT + c * WSTRIDE + k0;
    const float* src = W + tid;
    float v[16];
#pragma unroll
    for (int p = 0; p < 4; ++p) {
#pragma unroll
        for (int i = 0; i < 16; ++i) v[i] = src[(p * 16 + i) * 256];
#pragma unroll
        for (int i = 0; i < 16; ++i) dst[(p * 16 + i) * 2] = v[i];
    }
}

__device__ __forceinline__ void gn_rows_lds(const float acc0[8], const float acc1[8],
                                            float gw0, float gw1, float gb0, float gb1,
                                            bool relu, float* __restrict__ dst,
                                            int lc, int rg)
{
#pragma unroll
    for (int j = 0; j < 8; ++j) {
        float s1 = acc0[j] + acc1[j];
        float s2 = acc0[j] * acc0[j] + acc1[j] * acc1[j];
#pragma unroll
        for (int off = 32; off >= 1; off >>= 1) {
            s1 += __shfl_xor(s1, off);
            s2 += __shfl_xor(s2, off);
        }
        float m   = s1 * (1.f / 128.f);
        float var = fmaxf(s2 * (1.f / 128.f) - m * m, 0.f);
        float isc = rsqrtf(var + 1e-5f);
        float y0  = (acc0[j] - m) * isc * gw0 + gb0;
        float y1  = (acc1[j] - m) * isc * gw1 + gb1;
        if (relu) { y0 = fmaxf(y0, 0.f); y1 = fmaxf(y1, 0.f); }
        int r = rg * 8 + j;
        dst[r * WSTRIDE + lc]      = y0;
        dst[r * WSTRIDE + lc + 64] = y1;
    }
}

__global__ __launch_bounds__(256) void rowgemm_kernel(
    const float* __restrict__ X, const float* __restrict__ W,
    const float* __restrict__ gw, const float* __restrict__ gb,
    float* __restrict__ Y, int n, int gn_relu)
{
    __shared__ float sWT[128 * WSTRIDE];
    __shared__ float sX[TILE_E * WSTRIDE];
    const int tid  = threadIdx.x;
    const int base = blockIdx.x * TILE_E;

    {
        int r = tid >> 3, c0 = (tid & 7) * 16;
        int row = base + r;
        if (row < n) {
            const float* src = X + (size_t)row * 128 + c0;
            float*       dst = sX + r * WSTRIDE + c0;
#pragma unroll
            for (int i = 0; i < 4; ++i)
                *(float4*)(dst + i * 4) = *(const float4*)(src + i * 4);
        }
    }
    stage_wt(W, sWT, tid);
    __syncthreads();

    const int lc = tid & 63, rg = tid >> 6;
    float acc0[8] = {0,0,0,0,0,0,0,0}, acc1[8] = {0,0,0,0,0,0,0,0};
    gemm_tile(sX, sWT, lc, rg, acc0, acc1);

    if (gn_relu) {
        float gw0 = gw[lc], gw1 = gw[lc + 64], gb0 = gb[lc], gb1 = gb[lc + 64];
#pragma unroll
        for (int j = 0; j < 8; ++j) {
            float s1 = acc0[j] + acc1[j];
            float s2 = acc0[j] * acc0[j] + acc1[j] * acc1[j];
#pragma unroll
            for (int off = 32; off >= 1; off >>= 1) {
                s1 += __shfl_xor(s1, off);
                s2 += __shfl_xor(s2, off);
            }
            float m   = s1 * (1.f / 128.f);
            float var = fmaxf(s2 * (1.f / 128.f) - m * m, 0.f);
            float isc = rsqrtf(var + 1e-5f);
            int row = base + rg * 8 + j;
            if (row < n) {
                float y0 = fmaxf((acc0[j] - m) * isc * gw0 + gb0, 0.f);
                float y1 = fmaxf((acc1[j] - m) * isc * gw1 + gb1, 0.f);
                Y[(size_t)row * 128 + lc]      = y0;
                Y[(size_t)row * 128 + lc + 64] = y1;
            }
        }
    } else {
#pragma unroll
        for (int j = 0; j < 8; ++j) {
            int row = base + rg * 8 + j;
            if (row < n) {
                Y[(size_t)row * 128 + lc]      = acc0[j];
                Y[(size_t)row * 128 + lc + 64] = acc1[j];
            }
        }
    }
}

__global__ __launch_bounds__(256) void edge_kernel(
    const float* __restrict__ agt_ctrs, const float* __restrict__ ctx_ctrs,
    const int* __restrict__ hi, const int* __restrict__ wi,
    const float* __restrict__ qsrc, const float* __restrict__ ctx,
    const float* __restrict__ dist_w1, const float* __restrict__ dist_b1,
    const float* __restrict__ dist_w2,
    const float* __restrict__ dist_gw, const float* __restrict__ dist_gb,
    const float* __restrict__ q_w,
    const float* __restrict__ q_gw, const float* __restrict__ q_gb,
    const float* __restrict__ ctx_w1,
    const float* __restrict__ ctx_gw, const float* __restrict__ ctx_gb,
    const float* __restrict__ ctx_w2,
    float* __restrict__ out, int E, int numTiles, int q_pre)
{
    __shared__ float sWT[128 * WSTRIDE];
    __shared__ float sH2[TILE_E * WSTRIDE];
    __shared__ float sD2[TILE_E * WSTRIDE];
    __shared__ float sQ2[TILE_E * WSTRIDE];
    __shared__ float sC2[TILE_E * WSTRIDE];
    __shared__ int   sHi[TILE_E];
    __shared__ int   sWiB[TILE_E];
    __shared__ float sDx2[TILE_E], sDy2[TILE_E];

    const int tid = threadIdx.x;
    const int lc = tid & 63, rg = tid >> 6;

    const float dgw0 = dist_gw[lc], dgw1 = dist_gw[lc + 64];
    const float dgb0 = dist_gb[lc], dgb1 = dist_gb[lc + 64];
    const float cgw0 = ctx_gw[lc],  cgw1 = ctx_gw[lc + 64];
    const float cgb0 = ctx_gb[lc],  cgb1 = ctx_gb[lc + 64];
    float qgw0 = 0, qgw1 = 0, qgb0 = 0, qgb1 = 0;
    if (!q_pre) { qgw0 = q_gw[lc]; qgw1 = q_gw[lc + 64]; qgb0 = q_gb[lc]; qgb1 = q_gb[lc + 64]; }
    const int   hc  = tid & 127;
    const int   hrg = tid >> 7;
    const float w1x = dist_w1[hc], w1y = dist_w1[128 + hc], b1c = dist_b1[hc];

    for (int tile = blockIdx.x; tile < numTiles; tile += gridDim.x) {
        const int base = tile * TILE_E;
        __syncthreads();
        if (tid < TILE_E) {
            int e = base + tid;
            int h = 0, w = 0;
            if (e < E) { h = hi[e]; w = wi[e]; }
            sHi[tid]  = h;
            sWiB[tid] = w;
            sDx2[tid] = agt_ctrs[2 * h]     - ctx_ctrs[2 * w];
            sDy2[tid] = agt_ctrs[2 * h + 1] - ctx_ctrs[2 * w + 1];
        }
        __syncthreads();

        {
            int r = tid >> 3, c0 = (tid & 7) * 16;
            int h = sHi[r], w = sWiB[r];
            const float* qs = qsrc + (size_t)h * 128 + c0;
            const float* cs = ctx  + (size_t)w * 128 + c0;
            float* qd = sQ2 + r * WSTRIDE + c0;
            float* cd = sC2 + r * WSTRIDE + c0;
#pragma unroll
            for (int i = 0; i < 4; ++i) {
                *(float4*)(qd + i * 4) = *(const float4*)(qs + i * 4);
                *(float4*)(cd + i * 4) = *(const float4*)(cs + i * 4);
            }
        }
        {
#pragma unroll
            for (int j = 0; j < 16; ++j) {
                int r = hrg * 16 + j;
                float v = fmaf(sDx2[r], w1x, fmaf(sDy2[r], w1y, b1c));
                sH2[r * WSTRIDE + hc] = fmaxf(v, 0.f);
            }
        }

        if (!q_pre) {
            __syncthreads();
            stage_wt(q_w, sWT, tid);
            __syncthreads();
            float a0[8] = {0,0,0,0,0,0,0,0}, a1[8] = {0,0,0,0,0,0,0,0};
            gemm_tile(sQ2, sWT, lc, rg, a0, a1);
            __syncthreads();
            gn_rows_lds(a0, a1, qgw0, qgw1, qgb0, qgb1, true, sQ2, lc, rg);
        }

        __syncthreads();
        stage_wt(dist_w2, sWT, tid);
        __syncthreads();
        {
            float a0[8] = {0,0,0,0,0,0,0,0}, a1[8] = {0,0,0,0,0,0,0,0};
            gemm_tile(sH2, sWT, lc, rg, a0, a1);
            gn_rows_lds(a0, a1, dgw0, dgw1, dgb0, dgb1, true, sD2, lc, rg);
        }

        float m0[8] = {0,0,0,0,0,0,0,0}, m1[8] = {0,0,0,0,0,0,0,0};
        __syncthreads();
        stage_wt(ctx_w1, sWT, tid);
        __syncthreads();
        gemm_tile(sD2, sWT, lc, rg, m0, m1);
        __syncthreads();
        stage_wt(ctx_w1 + 128 * 128, sWT, tid);
        __syncthreads();
        gemm_tile(sQ2, sWT, lc, rg, m0, m1);
        __syncthreads();
        stage_wt(ctx_w1 + 2 * 128 * 128, sWT, tid);
        __syncthreads();
        gemm_tile(sC2, sWT, lc, rg, m0, m1);
        gn_rows_lds(m0, m1, cgw0, cgw1, cgb0, cgb1, true, sH2, lc, rg);

        __syncthreads();
        stage_wt(ctx_w2, sWT, tid);
        __syncthreads();
        {
            float a0[8] = {0,0,0,0,0,0,0,0}, a1[8] = {0,0,0,0,0,0,0,0};
            gemm_tile(sH2, sWT, lc, rg, a0, a1);
#pragma unroll
            for (int j = 0; j < 8; ++j) {
                int r = rg * 8 + j;
                int e = base + r;
                if (e < E) {
                    int h = sHi[r];
                    atomicAdd(&out[(size_t)h * 128 + lc],      a0[j]);
                    atomicAdd(&out[(size_t)h * 128 + lc + 64], a1[j]);
                }
            }
        }
    }
}

__global__ __launch_bounds__(256) void final_kernel(
    const float* __restrict__ agts,
    const float* __restrict__ norm_w, const float* __restrict__ norm_b,
    const float* __restrict__ lin_w,
    const float* __restrict__ lin_gw, const float* __restrict__ lin_gb,
    float* __restrict__ out, int n)
{
    __shared__ float sWT[128 * WSTRIDE];
    __shared__ float sX[TILE_E * WSTRIDE];
    const int tid  = threadIdx.x;
    const int base = blockIdx.x * TILE_E;

    {
        int r = tid >> 3, c0 = (tid & 7) * 16;
        int row = base + r;
        if (row < n) {
            const float* src = out + (size_t)row * 128 + c0;
            float vals[16];
            float s1 = 0.f, s2 = 0.f;
#pragma unroll
            for (int i = 0; i < 16; ++i) {
                float v = src[i];
                vals[i] = v; s1 += v; s2 += v * v;
            }
#pragma unroll
            for (int off = 4; off >= 1; off >>= 1) {
                s1 += __shfl_xor(s1, off);
                s2 += __shfl_xor(s2, off);
            }
            float m   = s1 * (1.f / 128.f);
            float var = fmaxf(s2 * (1.f / 128.f) - m * m, 0.f);
            float isc = rsqrtf(var + 1e-5f);
            float* dst = sX + r * WSTRIDE + c0;
#pragma unroll
            for (int i = 0; i < 16; ++i) {
                int c = c0 + i;
                float y = (vals[i] - m) * isc * norm_w[c] + norm_b[c];
                dst[i] = fmaxf(y, 0.f);
            }
        }
    }
    stage_wt(lin_w, sWT, tid);
    __syncthreads();

    const int lc = tid & 63, rg = tid >> 6;
    float acc0[8] = {0,0,0,0,0,0,0,0}, acc1[8] = {0,0,0,0,0,0,0,0};
    gemm_tile(sX, sWT, lc, rg, acc0, acc1);

    const float lgw0 = lin_gw[lc], lgw1 = lin_gw[lc + 64];
    const float lgb0 = lin_gb[lc], lgb1 = lin_gb[lc + 64];
#pragma unroll
    for (int j = 0; j < 8; ++j) {
        float s1 = acc0[j] + acc1[j];
        float s2 = acc0[j] * acc0[j] + acc1[j] * acc1[j];
#pragma unroll
        for (int off = 32; off >= 1; off >>= 1) {
            s1 += __shfl_xor(s1, off);
            s2 += __shfl_xor(s2, off);
        }
        float m   = s1 * (1.f / 128.f);
        float var = fmaxf(s2 * (1.f / 128.f) - m * m, 0.f);
        float isc = rsqrtf(var + 1e-5f);
        int row = base + rg * 8 + j;
        if (row < n) {
            size_t ro = (size_t)row * 128;
            float y0 = (acc0[j] - m) * isc * lgw0 + lgb0 + agts[ro + lc];
            float y1 = (acc1[j] - m) * isc * lgw1 + lgb1 + agts[ro + lc + 64];
            out[ro + lc]      = fmaxf(y0, 0.f);
            out[ro + lc + 64] = fmaxf(y1, 0.f);
        }
    }
}

// ---------------------------------------------------------------------------
extern "C" void kernel_launch(void* const* d_in, const int* in_sizes, int n_in,
                              void* d_out, int out_size, void* d_ws, size_t ws_size,
                              hipStream_t stream)
{
    const float* agts     = (const float*)d_in[0];
    const float* ctx      = (const float*)d_in[1];
    const float* agt_ctrs = (const float*)d_in[2];
    const float* ctx_ctrs = (const float*)d_in[3];
    const int*   hi       = (const int*)d_in[4];
    const int*   wi       = (const int*)d_in[5];
    const float* dist_w1  = (const float*)d_in[6];
    const float* dist_b1  = (const float*)d_in[7];
    const float* dist_w2  = (const float*)d_in[8];
    const float* dist_gw  = (const float*)d_in[9];
    const float* dist_gb  = (const float*)d_in[10];
    const float* q_w      = (const float*)d_in[11];
    const float* q_gw     = (const float*)d_in[12];
    const float* q_gb     = (const float*)d_in[13];
    const float* ctx_w1   = (const float*)d_in[14];
    const float* ctx_gw   = (const float*)d_in[15];
    const float* ctx_gb   = (const float*)d_in[16];
    const float* ctx_w2   = (const float*)d_in[17];
    const float* agt_w    = (const float*)d_in[18];
    const float* norm_w   = (const float*)d_in[19];
    const float* norm_b   = (const float*)d_in[20];
    const float* lin_w    = (const float*)d_in[21];
    const float* lin_gw   = (const float*)d_in[22];
    const float* lin_gb   = (const float*)d_in[23];

    const int N  = in_sizes[0] / 128;   // agents
    const int NC = in_sizes[1] / 128;   // ctx nodes
    const int E  = in_sizes[4];
    float* out = (float*)d_out;

    const int rowBlocksA = (N + 31) / 32;
    const int rowBlocksC = (NC + 31) / 32;
    const int numTiles   = (E + 31) / 32;

    const size_t needQM = (size_t)N  * 128 * sizeof(float);
    const size_t needCM = (size_t)NC * 128 * sizeof(float);

    if (ws_size >= needQM + needCM) {
        float* qm = (float*)d_ws;
        float* cm = (float*)((char*)d_ws + needQM);

        // node precomputes
        kq_kernel<<<rowBlocksA, 256, 0, stream>>>(agts, q_w, q_gw, q_gb,
                                                  ctx_w1 + 128 * 128, qm, N);
        kc_kernel<<<rowBlocksC, 256, 0, stream>>>(ctx, ctx_w1 + 2 * 128 * 128, cm, NC);
        // accumulator base: out = agts @ agt_w
        rowgemm_kernel<<<rowBlocksA, 256, 0, stream>>>(agts, agt_w, nullptr, nullptr, out, N, 0);
        // fused edge pipeline
        int gridE = numTiles < 2048 ? numTiles : 2048;
        edge_fused_kernel<<<gridE, 256, 0, stream>>>(agt_ctrs, ctx_ctrs, hi, wi,
            dist_w1, dist_b1, dist_w2, dist_gw, dist_gb,
            ctx_w1, ctx_gw, ctx_gb, ctx_w2,
            qm, cm, out, E, numTiles);
        // final row-wise
        final_kernel<<<rowBlocksA, 256, 0, stream>>>(agts, norm_w, norm_b,
            lin_w, lin_gw, lin_gb, out, N);
    } else {
        // fp32 fallback (no workspace needed)
        rowgemm_kernel<<<rowBlocksA, 256, 0, stream>>>(agts, agt_w, nullptr, nullptr, out, N, 0);
        int gridE = numTiles < 8192 ? numTiles : 8192;
        edge_kernel<<<gridE, 256, 0, stream>>>(agt_ctrs, ctx_ctrs, hi, wi,
            agts, ctx,
            dist_w1, dist_b1, dist_w2, dist_gw, dist_gb,
            q_w, q_gw, q_gb,
            ctx_w1, ctx_gw, ctx_gb, ctx_w2,
            out, E, numTiles, 0);
        final_kernel<<<rowBlocksA, 256, 0, stream>>>(agts, norm_w, norm_b,
            lin_w, lin_gw, lin_gb, out, N);
    }
}